// Round 1
// baseline (2037.088 us; speedup 1.0000x reference)
//
#include <hip/hip_runtime.h>
#include <math.h>

// RNN predictor: B=2048 samples, T=1024 teacher-forced steps, H=128 hidden,
// FUT=64 autoregressive steps. f32 throughout (no fp32 MFMA on CDNA4 -> VALU).
//
// Decomposition: block = 8 samples x 32 threads (thread owns a j-quad of the
// hidden state). Each sample's 32 threads live in ONE wave -> h write/read
// across steps is ordered by the in-order DS pipe, no __syncthreads in the
// 1088-step main loop. W_hh is staged transposed in LDS (wt[k][j]) so the
// inner product reads are contiguous ds_read_b128 (conflict-free; the wave's
// second sample reads identical addresses = broadcast).

#define BATCH 2048
#define TLEN  1024
#define FUT   64
#define HID   128
#define SPB   8     // samples per block
#define NT    256   // threads per block (8 waves of... 4 waves)

__device__ __forceinline__ float fast_tanh(float v) {
    // 1 - 2/(exp(2v)+1); saturates to +/-1 correctly for large |v|.
    return 1.0f - 2.0f / (__expf(2.0f * v) + 1.0f);
}

__global__ __launch_bounds__(NT, 1) void rnn_kernel(
    const float* __restrict__ x,      // [B, T]
    const float* __restrict__ W_ih,   // [H, 1]
    const float* __restrict__ W_hh,   // [H, H]
    const float* __restrict__ b_ih,   // [H]
    const float* __restrict__ b_hh,   // [H]
    const float* __restrict__ W_out,  // [1, H]
    const float* __restrict__ b_out,  // [1]
    float* __restrict__ out)          // [B, T+FUT]
{
    __shared__ float wt[HID * HID];          // wt[k*HID + j] = W_hh[j][k]
    __shared__ float hbuf[SPB][HID];         // hidden state per sample

    const int tid = threadIdx.x;
    const int sl  = tid >> 5;                // local sample 0..7
    const int jt  = tid & 31;                // j-quad index 0..31
    const int j0  = jt * 4;
    const int gs  = blockIdx.x * SPB + sl;   // global sample

    // Stage W_hh transposed: read coalesced along k, scatter into wt[k][j].
    for (int idx = tid; idx < HID * HID; idx += NT) {
        int j = idx >> 7;
        int k = idx & (HID - 1);
        wt[k * HID + j] = W_hh[idx];
    }
    for (int idx = tid; idx < SPB * HID; idx += NT)
        ((float*)hbuf)[idx] = 0.0f;
    __syncthreads();

    // Per-thread constants for its 4 hidden units.
    const float4 wih  = *(const float4*)&W_ih[j0];   // W_ih[:,0] contiguous
    const float4 biv  = *(const float4*)&b_ih[j0];
    const float4 bhv  = *(const float4*)&b_hh[j0];
    const float4 wout = *(const float4*)&W_out[j0];
    const float  bx = biv.x + bhv.x, by = biv.y + bhv.y;
    const float  bz = biv.z + bhv.z, bw = biv.w + bhv.w;
    const float  bo = b_out[0];

    const float* xrow = x + (size_t)gs * TLEN;
    float*       orow = out + (size_t)gs * (TLEN + FUT);
    const float* hrow = hbuf[sl];

    float o_prev = 0.0f;

    for (int i = 0; i < TLEN + FUT; ++i) {
        // Input: teacher-forced from x, then autoregressive from prev output.
        // Guarded load (not ternary) so the OOB address is never speculated.
        float inp = o_prev;
        if (i < TLEN) inp = xrow[i];

        float accx = 0.0f, accy = 0.0f, accz = 0.0f, accw = 0.0f;

        #pragma unroll 4
        for (int k4 = 0; k4 < HID / 4; ++k4) {
            const float4 hv = *(const float4*)&hrow[k4 * 4];
            const float* wp = &wt[(k4 * 4) * HID + j0];
            const float4 w0 = *(const float4*)(wp);
            const float4 w1 = *(const float4*)(wp + HID);
            const float4 w2 = *(const float4*)(wp + 2 * HID);
            const float4 w3 = *(const float4*)(wp + 3 * HID);
            accx = fmaf(hv.x, w0.x, accx); accy = fmaf(hv.x, w0.y, accy);
            accz = fmaf(hv.x, w0.z, accz); accw = fmaf(hv.x, w0.w, accw);
            accx = fmaf(hv.y, w1.x, accx); accy = fmaf(hv.y, w1.y, accy);
            accz = fmaf(hv.y, w1.z, accz); accw = fmaf(hv.y, w1.w, accw);
            accx = fmaf(hv.z, w2.x, accx); accy = fmaf(hv.z, w2.y, accy);
            accz = fmaf(hv.z, w2.z, accz); accw = fmaf(hv.z, w2.w, accw);
            accx = fmaf(hv.w, w3.x, accx); accy = fmaf(hv.w, w3.y, accy);
            accz = fmaf(hv.w, w3.z, accz); accw = fmaf(hv.w, w3.w, accw);
        }

        const float hx = fast_tanh(fmaf(inp, wih.x, accx + bx));
        const float hy = fast_tanh(fmaf(inp, wih.y, accy + by));
        const float hz = fast_tanh(fmaf(inp, wih.z, accz + bz));
        const float hw = fast_tanh(fmaf(inp, wih.w, accw + bw));

        // Publish new hidden state (read next step by this wave only; the
        // wave's single instruction stream + in-order DS pipe orders it).
        float4 hnew; hnew.x = hx; hnew.y = hy; hnew.z = hz; hnew.w = hw;
        *(float4*)&hbuf[sl][j0] = hnew;

        // Output projection: butterfly within the 32-lane sample group.
        float p = hx * wout.x + hy * wout.y + hz * wout.z + hw * wout.w;
        p += __shfl_xor(p, 1);
        p += __shfl_xor(p, 2);
        p += __shfl_xor(p, 4);
        p += __shfl_xor(p, 8);
        p += __shfl_xor(p, 16);
        const float o = p + bo;

        if (jt == 0) orow[i] = o;
        o_prev = o;
    }
}

extern "C" void kernel_launch(void* const* d_in, const int* in_sizes, int n_in,
                              void* d_out, int out_size, void* d_ws, size_t ws_size,
                              hipStream_t stream) {
    const float* x     = (const float*)d_in[0];
    const float* W_ih  = (const float*)d_in[1];
    const float* W_hh  = (const float*)d_in[2];
    const float* b_ih  = (const float*)d_in[3];
    const float* b_hh  = (const float*)d_in[4];
    const float* W_out = (const float*)d_in[5];
    const float* b_out = (const float*)d_in[6];
    float* out = (float*)d_out;

    dim3 grid(BATCH / SPB);   // 256 blocks -> 1 per CU
    dim3 block(NT);
    rnn_kernel<<<grid, block, 0, stream>>>(x, W_ih, W_hh, b_ih, b_hh,
                                           W_out, b_out, out);
}